// Round 6
// baseline (1461.848 us; speedup 1.0000x reference)
//
#include <hip/hip_runtime.h>
#include <hip/hip_bf16.h>
#include <hip/hip_cooperative_groups.h>

namespace cg = cooperative_groups;

// ============================================================================
// Hybrid matrix prefix scan:  res[k] = x @ (m_0 ... m_{k-1}),  N=1024, D=256.
// Deviation form everywhere: store P - I in bf16; combine is exact:
//   dev(XY) = devX + devY + devX@devY.
// Round 9:
//  (a) gemm tile body REVERTED to the proven 64x64 R7 structure (569us):
//      A frags direct to regs, full-K B in 32KiB LDS, ONE barrier before
//      MFMA, max memory-level parallelism. (R8's 4-step 128x128 was
//      latency-bound: 19% HBM, 3% MFMA, 21% occ -> reverted.)
//  (b) ALL 7 tree levels in ONE cooperative kernel (1024 blocks = 4/CU
//      guaranteed by launch_bounds(256,4) + 32KiB LDS; grid-stride jobs,
//      grid.sync() between levels). Kills 6 launch/drain boundaries, keeps
//      producer output L2-warm. Hedge: fall back to 7 launches on error.
//  (c) tail matvec loads vectorized x4 (ushort4/float4; 64 col-groups x
//      16 k-groups, ps[16][256] reduce) -- was scalar 2B bf16 loads.
// ============================================================================

#define D 256
#define DD 65536

typedef __attribute__((ext_vector_type(8))) short short8;
typedef __attribute__((ext_vector_type(4))) float f4;

__device__ __forceinline__ float bf2f(unsigned short u) {
  return __uint_as_float(((unsigned)u) << 16);
}
__device__ __forceinline__ unsigned short f2bf(float f) {
  __hip_bfloat16 h = __float2bfloat16(f);
  unsigned short u;
  __builtin_memcpy(&u, &h, 2);
  return u;
}
__device__ __forceinline__ unsigned f2bf2(float lo, float hi) {
  __hip_bfloat162 h = __float22bfloat162_rn(make_float2(lo, hi));
  unsigned u;
  __builtin_memcpy(&u, &h, 4);
  return u;
}
// fragment-order slot lane index: frag reads lane-contiguous b128.
#define LSWZ(i15, lq) (((((i15) & 15)) + ((lq) << 4)) ^ (lq))

// One 64x64 output tile of out[mat] = devA + devB + devA@devB.
// Body identical to the R7/R4 proven kernel; bx->job, gridDim->njobs, plus a
// trailing barrier so the LDS can be reused by the caller's next job.
__device__ __forceinline__ void do_tile(
    const float* __restrict__ aF, const unsigned short* __restrict__ aBf,
    long aMul, long aOff,
    const float* __restrict__ bF, const unsigned short* __restrict__ bBf,
    long bMul, long bOff,
    unsigned short* __restrict__ out, int job, int njobs)
{
  __shared__ __attribute__((aligned(16))) unsigned short Bs[16384]; // 32 KiB

  const int  nmb = njobs >> 4;                    // mats this pass (mult of 8)
  const int  xcd = job & 7, q = job >> 3;
  const long mat = (long)(xcd * (nmb >> 3)) + (q >> 4);
  const int  tile = q & 15;
  const int  m0 = (tile >> 2) << 6, n0 = (tile & 3) << 6;
  const long aBase = (mat * aMul + aOff) * (long)DD;
  const long bBase = (mat * bMul + bOff) * (long)DD;
  const int t = threadIdx.x;
  const int w = t >> 6, l = t & 63, lm = l & 15, lq4 = l >> 4;
  const int lswz = l ^ lq4;

  // ---- A fragments straight to registers.
  const int R = m0 + (w << 4) + lm;
  short8 areg[8];
  if (aF) {
    const float* ap = aF + aBase + (long)R * D + (lq4 << 3);
#pragma unroll
    for (int kt = 0; kt < 8; ++kt) {
      float4 v0 = *(const float4*)(ap + (kt << 5));
      float4 v1 = *(const float4*)(ap + (kt << 5) + 4);
      if ((R >> 3) == (kt << 2) + lq4) {          // diag fixup (one strip)
        const int j = R & 7;
        if      (j == 0) v0.x -= 1.f;
        else if (j == 1) v0.y -= 1.f;
        else if (j == 2) v0.z -= 1.f;
        else if (j == 3) v0.w -= 1.f;
        else if (j == 4) v1.x -= 1.f;
        else if (j == 5) v1.y -= 1.f;
        else if (j == 6) v1.z -= 1.f;
        else             v1.w -= 1.f;
      }
      union { short8 v8; unsigned u[4]; } ou;
      ou.u[0] = f2bf2(v0.x, v0.y);
      ou.u[1] = f2bf2(v0.z, v0.w);
      ou.u[2] = f2bf2(v1.x, v1.y);
      ou.u[3] = f2bf2(v1.z, v1.w);
      areg[kt] = ou.v8;
    }
  } else {
    const unsigned short* ap = aBf + aBase + (long)R * D + (lq4 << 3);
#pragma unroll
    for (int kt = 0; kt < 8; ++kt)
      areg[kt] = *(const short8*)(ap + (kt << 5));
  }

  // ---- stage B cols [n0,n0+64) x k[0,256) (register transpose into LDS)
  {
    const int n4 = (t & 15) << 2;
    const int kb0 = (t >> 4) << 3;
    const int gn = n0 + n4;
#pragma unroll
    for (int kp = 0; kp < 2; ++kp) {
      const int k8 = kb0 + (kp << 7);
      const int lq = (k8 >> 3) & 3, kt = k8 >> 5;
      if (bF) {
        unsigned tmpu[4][4];
        const int rel = gn - k8;
#pragma unroll
        for (int h = 0; h < 2; ++h) {
          float4 va[2], vb[2];
#pragma unroll
          for (int p2 = 0; p2 < 2; ++p2) {
            va[p2] = *(const float4*)(bF + bBase + (long)(k8 + 4 * h + 2 * p2) * D + gn);
            vb[p2] = *(const float4*)(bF + bBase + (long)(k8 + 4 * h + 2 * p2 + 1) * D + gn);
          }
          if (rel == 4 * h) {
            va[0].x -= 1.f; vb[0].y -= 1.f; va[1].z -= 1.f; vb[1].w -= 1.f;
          }
          tmpu[0][2 * h + 0] = f2bf2(va[0].x, vb[0].x);
          tmpu[0][2 * h + 1] = f2bf2(va[1].x, vb[1].x);
          tmpu[1][2 * h + 0] = f2bf2(va[0].y, vb[0].y);
          tmpu[1][2 * h + 1] = f2bf2(va[1].y, vb[1].y);
          tmpu[2][2 * h + 0] = f2bf2(va[0].z, vb[0].z);
          tmpu[2][2 * h + 1] = f2bf2(va[1].z, vb[1].z);
          tmpu[3][2 * h + 0] = f2bf2(va[0].w, vb[0].w);
          tmpu[3][2 * h + 1] = f2bf2(va[1].w, vb[1].w);
        }
#pragma unroll
        for (int jj = 0; jj < 4; ++jj) {
          const int n = n4 + jj;
          const int slot = (((n >> 4) << 3) + kt) * 64 + LSWZ(n, lq);
          uint4 st = { tmpu[jj][0], tmpu[jj][1], tmpu[jj][2], tmpu[jj][3] };
          *(uint4*)&Bs[slot << 3] = st;
        }
      } else {
        __attribute__((aligned(16))) unsigned short tmp[4][8];
#pragma unroll
        for (int kk = 0; kk < 8; ++kk) {
          const ushort4 v = *(const ushort4*)(bBf + bBase + (long)(k8 + kk) * D + gn);
          tmp[0][kk] = v.x; tmp[1][kk] = v.y; tmp[2][kk] = v.z; tmp[3][kk] = v.w;
        }
#pragma unroll
        for (int jj = 0; jj < 4; ++jj) {
          const int n = n4 + jj;
          const int slot = (((n >> 4) << 3) + kt) * 64 + LSWZ(n, lq);
          *(uint4*)&Bs[slot << 3] = *(const uint4*)&tmp[jj][0];
        }
      }
    }
  }
  __syncthreads();

  // ---- MFMA: A from registers, B frags lane-contiguous from LDS
  f4 acc[4] = {{0.f,0.f,0.f,0.f},{0.f,0.f,0.f,0.f},
               {0.f,0.f,0.f,0.f},{0.f,0.f,0.f,0.f}};
#pragma unroll
  for (int kt = 0; kt < 8; ++kt) {
#pragma unroll
    for (int f = 0; f < 4; ++f) {
      const short8 b = *(const short8*)&Bs[((((f << 3) + kt) << 6) + lswz) << 3];
      acc[f] = __builtin_amdgcn_mfma_f32_16x16x32_bf16(areg[kt], b, acc[f], 0, 0, 0);
    }
  }

  // ---- epilogue: s = acc + devA (global re-read, L2-hot) + devB (LDS)
#pragma unroll
  for (int f = 0; f < 4; ++f) {
    const int gj_l = (f << 4) + lm;
    const int gj   = n0 + gj_l;
#pragma unroll
    for (int r = 0; r < 4; ++r) {
      const int gi_l = (w << 4) + (lq4 << 2) + r;
      const int giG  = m0 + gi_l;
      float da;
      if (aF)
        da = aF[aBase + (long)giG * D + gj] - ((giG == gj) ? 1.f : 0.f);
      else
        da = bf2f(aBf[aBase + (long)giG * D + gj]);
      const int lqB  = (giG >> 3) & 3;
      const int slotB = (((gj_l >> 4) << 3) + (giG >> 5)) * 64 + LSWZ(gj_l, lqB);
      const float db = bf2f(Bs[(slotB << 3) + (giG & 7)]);
      acc[f][r] += da + db;
    }
  }
  __syncthreads();                                // all Bs reads done

  // ---- C restage (pitch 66) then coalesced store
  unsigned short* Cs = Bs;
#pragma unroll
  for (int f = 0; f < 4; ++f)
#pragma unroll
    for (int r = 0; r < 4; ++r)
      Cs[((w << 4) + (lq4 << 2) + r) * 66 + (f << 4) + lm] = f2bf(acc[f][r]);
  __syncthreads();
  {
    const int row = t >> 2, c0g = (t & 3) << 4;
    const unsigned int* Cw = (const unsigned int*)Cs;
    const int wb = row * 33 + ((t & 3) << 3);
    unsigned int wbuf[8];
#pragma unroll
    for (int i = 0; i < 8; ++i) wbuf[i] = Cw[wb + i];
    unsigned short* og = out + mat * (long)DD + (long)(m0 + row) * D + n0 + c0g;
    uint4 o0 = { wbuf[0], wbuf[1], wbuf[2], wbuf[3] };
    uint4 o1 = { wbuf[4], wbuf[5], wbuf[6], wbuf[7] };
    *(uint4*)og = o0;
    *((uint4*)og + 1) = o1;
  }
  __syncthreads();                                // LDS safe for next job
}

// Narrow-path / fallback wrapper: one tile per block.
__global__ __launch_bounds__(256, 4) void gemm_mfma(
    const float* __restrict__ aF, const unsigned short* __restrict__ aBf,
    long aMul, long aOff,
    const float* __restrict__ bF, const unsigned short* __restrict__ bBf,
    long bMul, long bOff,
    unsigned short* __restrict__ out)
{
  do_tile(aF, aBf, aMul, aOff, bF, bBf, bMul, bOff, out, blockIdx.x, gridDim.x);
}

// All 7 tree levels in one cooperative kernel. 1024 blocks (4/CU resident:
// launch_bounds(256,4) caps VGPR<=128; 32KiB LDS -> 5/CU). Grid-stride jobs
// per level; grid.sync() between levels.
__global__ __launch_bounds__(256, 4) void tree_coop(
    const float* __restrict__ m,
    unsigned short* __restrict__ T2,  unsigned short* __restrict__ Qb,
    unsigned short* __restrict__ Q2,  unsigned short* __restrict__ Q4,
    unsigned short* __restrict__ Rm,  unsigned short* __restrict__ S64,
    unsigned short* __restrict__ S128)
{
  cg::grid_group grid = cg::this_grid();
  unsigned short* outs[7] = {T2, Qb, Q2, Q4, Rm, S64, S128};
#pragma unroll 1
  for (int lev = 0; lev < 7; ++lev) {
    const int njobs = 8192 >> lev;
    const float* aF = (lev == 0) ? m : nullptr;
    const unsigned short* aB = (lev == 0) ? nullptr : outs[lev - 1];
#pragma unroll 1
    for (int job = blockIdx.x; job < njobs; job += gridDim.x)
      do_tile(aF, aB, 2, 0, aF, aB, 2, 1, outs[lev], job, njobs);
    grid.sync();
  }
}

// v = v + v @ dev(M), vectorized: 64 col-groups (4 cols) x 16 k-groups (16 i).
__device__ __forceinline__ void apply_bf16(const unsigned short* __restrict__ Mb,
                                           float* v, float (*ps)[D],
                                           int t, int col4, int q) {
  const unsigned short* Mp = Mb + (long)(q * 16) * D + col4;
  float a0 = 0.f, a1 = 0.f, a2 = 0.f, a3 = 0.f;
#pragma unroll
  for (int i = 0; i < 16; ++i) {
    const ushort4 u = *(const ushort4*)(Mp + (long)i * D);
    const float vi = v[q * 16 + i];
    a0 += vi * bf2f(u.x); a1 += vi * bf2f(u.y);
    a2 += vi * bf2f(u.z); a3 += vi * bf2f(u.w);
  }
  *(float4*)&ps[q][col4] = make_float4(a0, a1, a2, a3);
  __syncthreads();
  if (t < D) {
    float s = 0.f;
#pragma unroll
    for (int j = 0; j < 16; ++j) s += ps[j][t];
    v[t] += s;
  }
  __syncthreads();
}

// ONE kernel for the whole tail. WG c targets prefix length L = 4c:
// greedy span descent (128*,64,32,16,8,4), then exact fp32 bottom mat-vecs.
__global__ __launch_bounds__(1024) void tail_fused(
    const float* __restrict__ x,
    const unsigned short* __restrict__ sp128, const unsigned short* __restrict__ sp64,
    const unsigned short* __restrict__ sp32,  const unsigned short* __restrict__ sp16,
    const unsigned short* __restrict__ sp8,   const unsigned short* __restrict__ sp4,
    const float* __restrict__ m, float* __restrict__ out)
{
  __shared__ float v[D];
  __shared__ float ps[16][D];
  const int c = blockIdx.x, t = threadIdx.x;
  const int col4 = (t & 63) << 2, q = t >> 6;     // 64 col-groups x 16 k-groups
  if (t < D) v[t] = x[t];
  __syncthreads();
  const int L = c << 2;

  int pos = 0;
#pragma unroll 1
  while (pos + 128 <= L) { apply_bf16(sp128 + (long)(pos >> 7) * DD, v, ps, t, col4, q); pos += 128; }
  if (pos + 64 <= L) { apply_bf16(sp64 + (long)(pos >> 6) * DD, v, ps, t, col4, q); pos += 64; }
  if (pos + 32 <= L) { apply_bf16(sp32 + (long)(pos >> 5) * DD, v, ps, t, col4, q); pos += 32; }
  if (pos + 16 <= L) { apply_bf16(sp16 + (long)(pos >> 4) * DD, v, ps, t, col4, q); pos += 16; }
  if (pos + 8 <= L)  { apply_bf16(sp8  + (long)(pos >> 3) * DD, v, ps, t, col4, q); pos += 8; }
  if (pos + 4 <= L)  { apply_bf16(sp4  + (long)(pos >> 2) * DD, v, ps, t, col4, q); pos += 4; }

  // bottom: emit rows with exact fp32 mat-vecs over m (float4 loads)
  if (t < D) out[(long)L * D + t] = v[t];
  const int steps = (c == 255) ? 4 : 3;
#pragma unroll 1
  for (int s = 0; s < steps; ++s) {
    const float* Mp = m + (long)(L + s) * DD + (long)(q * 16) * D + col4;
    float a0 = 0.f, a1 = 0.f, a2 = 0.f, a3 = 0.f;
#pragma unroll
    for (int i = 0; i < 16; ++i) {
      const float4 u = *(const float4*)(Mp + (long)i * D);
      const float vi = v[q * 16 + i];
      a0 += vi * u.x; a1 += vi * u.y; a2 += vi * u.z; a3 += vi * u.w;
    }
    *(float4*)&ps[q][col4] = make_float4(a0, a1, a2, a3);
    __syncthreads();
    if (t < D) {
      float s2 = 0.f;
#pragma unroll
      for (int j = 0; j < 16; ++j) s2 += ps[j][t];
      v[t] = s2;
      out[(long)(L + s + 1) * D + t] = s2;
    }
    __syncthreads();
  }
}

// correctness-only fallback if ws is too small: fully sequential chain
__global__ __launch_bounds__(256) void fallback_seq(
    const float* __restrict__ x, const float* __restrict__ m,
    float* __restrict__ out)
{
  __shared__ float v[D];
  const int t = threadIdx.x;
  v[t] = x[t];
  __syncthreads();
  for (int k = 0; k < 1024; ++k) {
    out[(long)k * D + t] = v[t];
    const float* M = m + (long)k * DD;
    float acc = 0.f;
    for (int i = 0; i < D; ++i) acc += v[i] * M[(long)i * D + t];
    __syncthreads();
    v[t] = acc;
    __syncthreads();
  }
  out[(long)1024 * D + t] = v[t];
}

extern "C" void kernel_launch(void* const* d_in, const int* in_sizes, int n_in,
                              void* d_out, int out_size, void* d_ws, size_t ws_size,
                              hipStream_t stream) {
  const float* x = (const float*)d_in[0];   // [1,256] fp32
  const float* m = (const float*)d_in[1];   // [1024,256,256] fp32
  float* out = (float*)d_out;               // [1025,256] fp32

  char* w8 = (char*)d_ws;
  const size_t MB = 1048576;
  const dim3 blk(256), vblk(1024);

  if (ws_size >= 127 * MB) {
    // ---- wide path: co-op tree (1 launch) + fused tail (1 launch)
    unsigned short* T2   = (unsigned short*)(w8);             // 64 MiB span-2  (512)
    unsigned short* Qb   = (unsigned short*)(w8 + 64 * MB);   // 32 MiB span-4  (256)
    unsigned short* Q2   = (unsigned short*)(w8 + 96 * MB);   // 16 MiB span-8  (128)
    unsigned short* Q4   = (unsigned short*)(w8 + 112 * MB);  //  8 MiB span-16 (64)
    unsigned short* Rm   = (unsigned short*)(w8 + 120 * MB);  //  4 MiB span-32 (32)
    unsigned short* S64  = (unsigned short*)(w8 + 124 * MB);  //  2 MiB span-64 (16)
    unsigned short* S128 = (unsigned short*)(w8 + 126 * MB);  //  1 MiB span-128 (8)
    const float* mm = m;
    void* args[] = { (void*)&mm, (void*)&T2, (void*)&Qb, (void*)&Q2,
                     (void*)&Q4, (void*)&Rm, (void*)&S64, (void*)&S128 };
    hipError_t e = hipLaunchCooperativeKernel((const void*)tree_coop,
                                              dim3(1024), blk, args, 0, stream);
    if (e != hipSuccess) {
      // hedge: sequential level launches (identical math)
      gemm_mfma<<<dim3(8192), blk, 0, stream>>>(m, nullptr, 2, 0, m, nullptr, 2, 1, T2);
      gemm_mfma<<<dim3(4096), blk, 0, stream>>>(nullptr, T2, 2, 0, nullptr, T2, 2, 1, Qb);
      gemm_mfma<<<dim3(2048), blk, 0, stream>>>(nullptr, Qb, 2, 0, nullptr, Qb, 2, 1, Q2);
      gemm_mfma<<<dim3(1024), blk, 0, stream>>>(nullptr, Q2, 2, 0, nullptr, Q2, 2, 1, Q4);
      gemm_mfma<<<dim3(512),  blk, 0, stream>>>(nullptr, Q4, 2, 0, nullptr, Q4, 2, 1, Rm);
      gemm_mfma<<<dim3(256),  blk, 0, stream>>>(nullptr, Rm, 2, 0, nullptr, Rm, 2, 1, S64);
      gemm_mfma<<<dim3(128),  blk, 0, stream>>>(nullptr, S64, 2, 0, nullptr, S64, 2, 1, S128);
    }
    tail_fused<<<dim3(256), vblk, 0, stream>>>(x, S128, S64, Rm, Q4, Q2, Qb, m, out);
  } else if (ws_size >= 67108864) {
    // ---- narrow path (half-split tree), fused tail
    unsigned short* buf0 = (unsigned short*)(w8);
    unsigned short* Qb   = (unsigned short*)(w8 + 33554432);  // span-4, 256 mats
    unsigned short* Q2   = (unsigned short*)(w8);             // 16 MiB span-8
    unsigned short* Q4   = (unsigned short*)(w8 + 16777216);  //  8 MiB span-16
    unsigned short* Rm   = (unsigned short*)(w8 + 25165824);  //  4 MiB span-32
    unsigned short* S64  = (unsigned short*)(w8 + 29360128);  //  2 MiB span-64
    unsigned short* S128 = (unsigned short*)(w8 + 31457280);  //  1 MiB span-128
    gemm_mfma<<<dim3(4096), blk, 0, stream>>>(m, nullptr, 2, 0, m, nullptr, 2, 1, buf0);
    gemm_mfma<<<dim3(2048), blk, 0, stream>>>(nullptr, buf0, 2, 0, nullptr, buf0, 2, 1, Qb);
    gemm_mfma<<<dim3(4096), blk, 0, stream>>>(m + 512L * DD, nullptr, 2, 0,
                                              m + 512L * DD, nullptr, 2, 1, buf0);
    gemm_mfma<<<dim3(2048), blk, 0, stream>>>(nullptr, buf0, 2, 0, nullptr, buf0, 2, 1,
                                              Qb + 128L * DD);
    gemm_mfma<<<dim3(2048), blk, 0, stream>>>(nullptr, Qb, 2, 0, nullptr, Qb, 2, 1, Q2);
    gemm_mfma<<<dim3(1024), blk, 0, stream>>>(nullptr, Q2, 2, 0, nullptr, Q2, 2, 1, Q4);
    gemm_mfma<<<dim3(512),  blk, 0, stream>>>(nullptr, Q4, 2, 0, nullptr, Q4, 2, 1, Rm);
    gemm_mfma<<<dim3(256),  blk, 0, stream>>>(nullptr, Rm, 2, 0, nullptr, Rm, 2, 1, S64);
    gemm_mfma<<<dim3(128),  blk, 0, stream>>>(nullptr, S64, 2, 0, nullptr, S64, 2, 1, S128);
    tail_fused<<<dim3(256), vblk, 0, stream>>>(x, S128, S64, Rm, Q4, Q2, Qb, m, out);
  } else {
    fallback_seq<<<dim3(1), blk, 0, stream>>>(x, m, out);
  }
}

// Round 7
// 565.505 us; speedup vs baseline: 2.5850x; 2.5850x over previous
//
#include <hip/hip_runtime.h>
#include <hip/hip_bf16.h>

// ============================================================================
// Hybrid matrix prefix scan:  res[k] = x @ (m_0 ... m_{k-1}),  N=1024, D=256.
// Deviation form everywhere: store P - I in bf16; combine is exact:
//   dev(XY) = devX + devY + devX@devY.
// Round 10: REVERT tree to the measured-best R7 config (569us: 7 per-level
// launches, 64x64 tile, launch_bounds(256,4), two-pass B staging, A frags in
// registers, full-K LDS, single barrier) -- the R9 coop fusion spilled
// (VGPR 64 < ~100 live) and ran 4x slow. KEEP the one verified improvement
// from R9: vectorized tail (ushort4/float4 loads, 16-way ps reduce), which
// passed numerically. Single-variable A/B vs the 569us baseline.
// ============================================================================

#define D 256
#define DD 65536

typedef __attribute__((ext_vector_type(8))) short short8;
typedef __attribute__((ext_vector_type(4))) float f4;

__device__ __forceinline__ float bf2f(unsigned short u) {
  return __uint_as_float(((unsigned)u) << 16);
}
__device__ __forceinline__ unsigned short f2bf(float f) {
  __hip_bfloat16 h = __float2bfloat16(f);
  unsigned short u;
  __builtin_memcpy(&u, &h, 2);
  return u;
}
__device__ __forceinline__ unsigned f2bf2(float lo, float hi) {
  __hip_bfloat162 h = __float22bfloat162_rn(make_float2(lo, hi));
  unsigned u;
  __builtin_memcpy(&u, &h, 4);
  return u;
}
// fragment-order slot lane index: frag reads lane-contiguous b128.
#define LSWZ(i15, lq) (((((i15) & 15)) + ((lq) << 4)) ^ (lq))

// out[mat] = devA + devB + devA@devB (bf16 dev out), MFMA 16x16x32 bf16.
// 64x64 tile/block (16 blocks/mat), 4 waves. B staged full-K in LDS (32 KiB);
// A fragments live in registers. Block swizzle: xcd = bx&7; all 16 tiles of a
// mat on the same XCD (requires gridDim/16 divisible by 8).
__global__ __launch_bounds__(256, 4) void gemm_mfma(
    const float* __restrict__ aF, const unsigned short* __restrict__ aBf,
    long aMul, long aOff,
    const float* __restrict__ bF, const unsigned short* __restrict__ bBf,
    long bMul, long bOff,
    unsigned short* __restrict__ out)
{
  __shared__ __attribute__((aligned(16))) unsigned short Bs[16384]; // 32 KiB

  const int  bx  = blockIdx.x;
  const int  nmb = ((int)gridDim.x) >> 4;         // mats this dispatch (mult of 8)
  const int  xcd = bx & 7, q = bx >> 3;
  const long mat = (long)(xcd * (nmb >> 3)) + (q >> 4);
  const int  tile = q & 15;
  const int  m0 = (tile >> 2) << 6, n0 = (tile & 3) << 6;
  const long aBase = (mat * aMul + aOff) * (long)DD;
  const long bBase = (mat * bMul + bOff) * (long)DD;
  const int t = threadIdx.x;
  const int w = t >> 6, l = t & 63, lm = l & 15, lq4 = l >> 4;
  const int lswz = l ^ lq4;

  // ---- A fragments straight to registers.
  // Lane l of wave w feeds MFMA row R = m0+16w+(l&15), k = 32kt + 8*lq4 + j.
  const int R = m0 + (w << 4) + lm;
  short8 areg[8];
  if (aF) {
    const float* ap = aF + aBase + (long)R * D + (lq4 << 3);
#pragma unroll
    for (int kt = 0; kt < 8; ++kt) {
      float4 v0 = *(const float4*)(ap + (kt << 5));
      float4 v1 = *(const float4*)(ap + (kt << 5) + 4);
      // diag fixup: row R's diagonal col R lies in this 8-k strip iff
      // (R>>3) == 4*kt + lq4; then the component is j = R & 7.
      if ((R >> 3) == (kt << 2) + lq4) {
        const int j = R & 7;
        if      (j == 0) v0.x -= 1.f;
        else if (j == 1) v0.y -= 1.f;
        else if (j == 2) v0.z -= 1.f;
        else if (j == 3) v0.w -= 1.f;
        else if (j == 4) v1.x -= 1.f;
        else if (j == 5) v1.y -= 1.f;
        else if (j == 6) v1.z -= 1.f;
        else             v1.w -= 1.f;
      }
      union { short8 v8; unsigned u[4]; } ou;
      ou.u[0] = f2bf2(v0.x, v0.y);
      ou.u[1] = f2bf2(v0.z, v0.w);
      ou.u[2] = f2bf2(v1.x, v1.y);
      ou.u[3] = f2bf2(v1.z, v1.w);
      areg[kt] = ou.v8;
    }
  } else {
    const unsigned short* ap = aBf + aBase + (long)R * D + (lq4 << 3);
#pragma unroll
    for (int kt = 0; kt < 8; ++kt)
      areg[kt] = *(const short8*)(ap + (kt << 5));
  }

  // ---- stage B cols [n0,n0+64) x k[0,256) (register transpose into LDS)
  {
    const int n4 = (t & 15) << 2;
    const int kb0 = (t >> 4) << 3;
    const int gn = n0 + n4;
#pragma unroll
    for (int kp = 0; kp < 2; ++kp) {
      const int k8 = kb0 + (kp << 7);
      const int lq = (k8 >> 3) & 3, kt = k8 >> 5;
      if (bF) {
        // two-pass staging (va[2]/vb[2]): low VGPR pressure, no spill at 128.
        unsigned tmpu[4][4];
        const int rel = gn - k8;
#pragma unroll
        for (int h = 0; h < 2; ++h) {
          float4 va[2], vb[2];
#pragma unroll
          for (int p2 = 0; p2 < 2; ++p2) {
            va[p2] = *(const float4*)(bF + bBase + (long)(k8 + 4 * h + 2 * p2) * D + gn);
            vb[p2] = *(const float4*)(bF + bBase + (long)(k8 + 4 * h + 2 * p2 + 1) * D + gn);
          }
          // cols [gn,gn+4) have diag rows [gn,gn+4); they fall in this
          // 4-row half iff rel == 4h (gn,k8 4-/8-aligned).
          if (rel == 4 * h) {
            va[0].x -= 1.f; vb[0].y -= 1.f; va[1].z -= 1.f; vb[1].w -= 1.f;
          }
          tmpu[0][2 * h + 0] = f2bf2(va[0].x, vb[0].x);
          tmpu[0][2 * h + 1] = f2bf2(va[1].x, vb[1].x);
          tmpu[1][2 * h + 0] = f2bf2(va[0].y, vb[0].y);
          tmpu[1][2 * h + 1] = f2bf2(va[1].y, vb[1].y);
          tmpu[2][2 * h + 0] = f2bf2(va[0].z, vb[0].z);
          tmpu[2][2 * h + 1] = f2bf2(va[1].z, vb[1].z);
          tmpu[3][2 * h + 0] = f2bf2(va[0].w, vb[0].w);
          tmpu[3][2 * h + 1] = f2bf2(va[1].w, vb[1].w);
        }
#pragma unroll
        for (int jj = 0; jj < 4; ++jj) {
          const int n = n4 + jj;
          const int slot = (((n >> 4) << 3) + kt) * 64 + LSWZ(n, lq);
          uint4 st = { tmpu[jj][0], tmpu[jj][1], tmpu[jj][2], tmpu[jj][3] };
          *(uint4*)&Bs[slot << 3] = st;
        }
      } else {
        __attribute__((aligned(16))) unsigned short tmp[4][8];
#pragma unroll
        for (int kk = 0; kk < 8; ++kk) {
          const ushort4 v = *(const ushort4*)(bBf + bBase + (long)(k8 + kk) * D + gn);
          tmp[0][kk] = v.x; tmp[1][kk] = v.y; tmp[2][kk] = v.z; tmp[3][kk] = v.w;
        }
#pragma unroll
        for (int jj = 0; jj < 4; ++jj) {
          const int n = n4 + jj;
          const int slot = (((n >> 4) << 3) + kt) * 64 + LSWZ(n, lq);
          *(uint4*)&Bs[slot << 3] = *(const uint4*)&tmp[jj][0];
        }
      }
    }
  }
  __syncthreads();

  // ---- MFMA: A from registers, B frags lane-contiguous from LDS (32 b128)
  f4 acc[4] = {{0.f,0.f,0.f,0.f},{0.f,0.f,0.f,0.f},
               {0.f,0.f,0.f,0.f},{0.f,0.f,0.f,0.f}};
#pragma unroll
  for (int kt = 0; kt < 8; ++kt) {
#pragma unroll
    for (int f = 0; f < 4; ++f) {
      const short8 b = *(const short8*)&Bs[((((f << 3) + kt) << 6) + lswz) << 3];
      acc[f] = __builtin_amdgcn_mfma_f32_16x16x32_bf16(areg[kt], b, acc[f], 0, 0, 0);
    }
  }

  // ---- epilogue: s = acc + devA (global re-read, L2-hot) + devB (LDS)
#pragma unroll
  for (int f = 0; f < 4; ++f) {
    const int gj_l = (f << 4) + lm;
    const int gj   = n0 + gj_l;                   // A's k/col index
#pragma unroll
    for (int r = 0; r < 4; ++r) {
      const int gi_l = (w << 4) + (lq4 << 2) + r; // local row
      const int giG  = m0 + gi_l;                 // B's k index
      float da;
      if (aF)
        da = aF[aBase + (long)giG * D + gj] - ((giG == gj) ? 1.f : 0.f);
      else
        da = bf2f(aBf[aBase + (long)giG * D + gj]);
      const int lqB  = (giG >> 3) & 3;
      const int slotB = (((gj_l >> 4) << 3) + (giG >> 5)) * 64 + LSWZ(gj_l, lqB);
      const float db = bf2f(Bs[(slotB << 3) + (giG & 7)]);
      acc[f][r] += da + db;
    }
  }
  __syncthreads();                                // all Bs reads done

  // ---- C restage (pitch 66: conflict-free b16 writes) then coalesced store
  unsigned short* Cs = Bs;                        // reuse (4224 shorts)
#pragma unroll
  for (int f = 0; f < 4; ++f)
#pragma unroll
    for (int r = 0; r < 4; ++r)
      Cs[((w << 4) + (lq4 << 2) + r) * 66 + (f << 4) + lm] = f2bf(acc[f][r]);
  __syncthreads();
  {
    const int row = t >> 2, c0g = (t & 3) << 4;   // 16 shorts per thread
    const unsigned int* Cw = (const unsigned int*)Cs;
    const int wb = row * 33 + ((t & 3) << 3);
    unsigned int wbuf[8];
#pragma unroll
    for (int i = 0; i < 8; ++i) wbuf[i] = Cw[wb + i];
    unsigned short* og = out + mat * (long)DD + (long)(m0 + row) * D + n0 + c0g;
    uint4 o0 = { wbuf[0], wbuf[1], wbuf[2], wbuf[3] };
    uint4 o1 = { wbuf[4], wbuf[5], wbuf[6], wbuf[7] };
    *(uint4*)og = o0;
    *((uint4*)og + 1) = o1;
  }
}

// v = v + v @ dev(M), vectorized: 64 col-groups (4 cols) x 16 k-groups (16 i).
__device__ __forceinline__ void apply_bf16(const unsigned short* __restrict__ Mb,
                                           float* v, float (*ps)[D],
                                           int t, int col4, int q) {
  const unsigned short* Mp = Mb + (long)(q * 16) * D + col4;
  float a0 = 0.f, a1 = 0.f, a2 = 0.f, a3 = 0.f;
#pragma unroll
  for (int i = 0; i < 16; ++i) {
    const ushort4 u = *(const ushort4*)(Mp + (long)i * D);
    const float vi = v[q * 16 + i];
    a0 += vi * bf2f(u.x); a1 += vi * bf2f(u.y);
    a2 += vi * bf2f(u.z); a3 += vi * bf2f(u.w);
  }
  *(float4*)&ps[q][col4] = make_float4(a0, a1, a2, a3);
  __syncthreads();
  if (t < D) {
    float s = 0.f;
#pragma unroll
    for (int j = 0; j < 16; ++j) s += ps[j][t];
    v[t] += s;
  }
  __syncthreads();
}

// ONE kernel for the whole tail. WG c targets prefix length L = 4c:
// greedy span descent (128*,64,32,16,8,4), then exact fp32 bottom mat-vecs
// over m emitting out rows L..L+3 (c=255 also emits row 1024).
__global__ __launch_bounds__(1024) void tail_fused(
    const float* __restrict__ x,
    const unsigned short* __restrict__ sp128, const unsigned short* __restrict__ sp64,
    const unsigned short* __restrict__ sp32,  const unsigned short* __restrict__ sp16,
    const unsigned short* __restrict__ sp8,   const unsigned short* __restrict__ sp4,
    const float* __restrict__ m, float* __restrict__ out)
{
  __shared__ float v[D];
  __shared__ float ps[16][D];
  const int c = blockIdx.x, t = threadIdx.x;
  const int col4 = (t & 63) << 2, q = t >> 6;     // 64 col-groups x 16 k-groups
  if (t < D) v[t] = x[t];
  __syncthreads();
  const int L = c << 2;

  int pos = 0;
#pragma unroll 1
  while (pos + 128 <= L) { apply_bf16(sp128 + (long)(pos >> 7) * DD, v, ps, t, col4, q); pos += 128; }
  if (pos + 64 <= L) { apply_bf16(sp64 + (long)(pos >> 6) * DD, v, ps, t, col4, q); pos += 64; }
  if (pos + 32 <= L) { apply_bf16(sp32 + (long)(pos >> 5) * DD, v, ps, t, col4, q); pos += 32; }
  if (pos + 16 <= L) { apply_bf16(sp16 + (long)(pos >> 4) * DD, v, ps, t, col4, q); pos += 16; }
  if (pos + 8 <= L)  { apply_bf16(sp8  + (long)(pos >> 3) * DD, v, ps, t, col4, q); pos += 8; }
  if (pos + 4 <= L)  { apply_bf16(sp4  + (long)(pos >> 2) * DD, v, ps, t, col4, q); pos += 4; }

  // bottom: emit rows with exact fp32 mat-vecs over m (float4 loads)
  if (t < D) out[(long)L * D + t] = v[t];
  const int steps = (c == 255) ? 4 : 3;
#pragma unroll 1
  for (int s = 0; s < steps; ++s) {
    const float* Mp = m + (long)(L + s) * DD + (long)(q * 16) * D + col4;
    float a0 = 0.f, a1 = 0.f, a2 = 0.f, a3 = 0.f;
#pragma unroll
    for (int i = 0; i < 16; ++i) {
      const float4 u = *(const float4*)(Mp + (long)i * D);
      const float vi = v[q * 16 + i];
      a0 += vi * u.x; a1 += vi * u.y; a2 += vi * u.z; a3 += vi * u.w;
    }
    *(float4*)&ps[q][col4] = make_float4(a0, a1, a2, a3);
    __syncthreads();
    if (t < D) {
      float s2 = 0.f;
#pragma unroll
      for (int j = 0; j < 16; ++j) s2 += ps[j][t];
      v[t] = s2;
      out[(long)(L + s + 1) * D + t] = s2;
    }
    __syncthreads();
  }
}

// correctness-only fallback if ws is too small: fully sequential chain
__global__ __launch_bounds__(256) void fallback_seq(
    const float* __restrict__ x, const float* __restrict__ m,
    float* __restrict__ out)
{
  __shared__ float v[D];
  const int t = threadIdx.x;
  v[t] = x[t];
  __syncthreads();
  for (int k = 0; k < 1024; ++k) {
    out[(long)k * D + t] = v[t];
    const float* M = m + (long)k * DD;
    float acc = 0.f;
    for (int i = 0; i < D; ++i) acc += v[i] * M[(long)i * D + t];
    __syncthreads();
    v[t] = acc;
    __syncthreads();
  }
  out[(long)1024 * D + t] = v[t];
}

extern "C" void kernel_launch(void* const* d_in, const int* in_sizes, int n_in,
                              void* d_out, int out_size, void* d_ws, size_t ws_size,
                              hipStream_t stream) {
  const float* x = (const float*)d_in[0];   // [1,256] fp32
  const float* m = (const float*)d_in[1];   // [1024,256,256] fp32
  float* out = (float*)d_out;               // [1025,256] fp32

  char* w8 = (char*)d_ws;
  const size_t MB = 1048576;
  const dim3 blk(256), vblk(1024);

  if (ws_size >= 127 * MB) {
    // ---- wide path: full-width tree, one launch per level (7 gemms + tail)
    unsigned short* T2   = (unsigned short*)(w8);             // 64 MiB span-2  (512)
    unsigned short* Qb   = (unsigned short*)(w8 + 64 * MB);   // 32 MiB span-4  (256)
    unsigned short* Q2   = (unsigned short*)(w8 + 96 * MB);   // 16 MiB span-8  (128)
    unsigned short* Q4   = (unsigned short*)(w8 + 112 * MB);  //  8 MiB span-16 (64)
    unsigned short* Rm   = (unsigned short*)(w8 + 120 * MB);  //  4 MiB span-32 (32)
    unsigned short* S64  = (unsigned short*)(w8 + 124 * MB);  //  2 MiB span-64 (16)
    unsigned short* S128 = (unsigned short*)(w8 + 126 * MB);  //  1 MiB span-128 (8)
    gemm_mfma<<<dim3(8192), blk, 0, stream>>>(m, nullptr, 2, 0, m, nullptr, 2, 1, T2);
    gemm_mfma<<<dim3(4096), blk, 0, stream>>>(nullptr, T2, 2, 0, nullptr, T2, 2, 1, Qb);
    gemm_mfma<<<dim3(2048), blk, 0, stream>>>(nullptr, Qb, 2, 0, nullptr, Qb, 2, 1, Q2);
    gemm_mfma<<<dim3(1024), blk, 0, stream>>>(nullptr, Q2, 2, 0, nullptr, Q2, 2, 1, Q4);
    gemm_mfma<<<dim3(512),  blk, 0, stream>>>(nullptr, Q4, 2, 0, nullptr, Q4, 2, 1, Rm);
    gemm_mfma<<<dim3(256),  blk, 0, stream>>>(nullptr, Rm, 2, 0, nullptr, Rm, 2, 1, S64);
    gemm_mfma<<<dim3(128),  blk, 0, stream>>>(nullptr, S64, 2, 0, nullptr, S64, 2, 1, S128);
    tail_fused<<<dim3(256), vblk, 0, stream>>>(x, S128, S64, Rm, Q4, Q2, Qb, m, out);
  } else if (ws_size >= 67108864) {
    // ---- narrow path (half-split tree), fused tail
    unsigned short* buf0 = (unsigned short*)(w8);
    unsigned short* Qb   = (unsigned short*)(w8 + 33554432);  // span-4, 256 mats
    unsigned short* Q2   = (unsigned short*)(w8);             // 16 MiB span-8
    unsigned short* Q4   = (unsigned short*)(w8 + 16777216);  //  8 MiB span-16
    unsigned short* Rm   = (unsigned short*)(w8 + 25165824);  //  4 MiB span-32
    unsigned short* S64  = (unsigned short*)(w8 + 29360128);  //  2 MiB span-64
    unsigned short* S128 = (unsigned short*)(w8 + 31457280);  //  1 MiB span-128
    gemm_mfma<<<dim3(4096), blk, 0, stream>>>(m, nullptr, 2, 0, m, nullptr, 2, 1, buf0);
    gemm_mfma<<<dim3(2048), blk, 0, stream>>>(nullptr, buf0, 2, 0, nullptr, buf0, 2, 1, Qb);
    gemm_mfma<<<dim3(4096), blk, 0, stream>>>(m + 512L * DD, nullptr, 2, 0,
                                              m + 512L * DD, nullptr, 2, 1, buf0);
    gemm_mfma<<<dim3(2048), blk, 0, stream>>>(nullptr, buf0, 2, 0, nullptr, buf0, 2, 1,
                                              Qb + 128L * DD);
    gemm_mfma<<<dim3(2048), blk, 0, stream>>>(nullptr, Qb, 2, 0, nullptr, Qb, 2, 1, Q2);
    gemm_mfma<<<dim3(1024), blk, 0, stream>>>(nullptr, Q2, 2, 0, nullptr, Q2, 2, 1, Q4);
    gemm_mfma<<<dim3(512),  blk, 0, stream>>>(nullptr, Q4, 2, 0, nullptr, Q4, 2, 1, Rm);
    gemm_mfma<<<dim3(256),  blk, 0, stream>>>(nullptr, Rm, 2, 0, nullptr, Rm, 2, 1, S64);
    gemm_mfma<<<dim3(128),  blk, 0, stream>>>(nullptr, S64, 2, 0, nullptr, S64, 2, 1, S128);
    tail_fused<<<dim3(256), vblk, 0, stream>>>(x, S128, S64, Rm, Q4, Q2, Qb, m, out);
  } else {
    fallback_seq<<<dim3(1), blk, 0, stream>>>(x, m, out);
  }
}